// Round 3
// baseline (1390.096 us; speedup 1.0000x reference)
//
#include <hip/hip_runtime.h>
#include <hip/hip_bf16.h>

typedef __bf16 bf16;
typedef __attribute__((ext_vector_type(8))) __bf16 bf16x8;
typedef __attribute__((ext_vector_type(4))) float f32x4;

#define E_EDGES 262144
#define MT 128   // rows per block

// Pre-pass: transpose + fp32->bf16 convert weights into workspace.
// W1 fp32 [384][512] -> W1t bf16 [512][384];  W2 fp32 [512][128] -> W2t bf16 [128][512]
__global__ void transpose_w(const float* __restrict__ W1, const float* __restrict__ W2,
                            bf16* __restrict__ W1t, bf16* __restrict__ W2t)
{
  int tid = blockIdx.x * 256 + threadIdx.x;
  if (tid < 512 * 384) {
    int n = tid / 384;
    int k = tid - n * 384;
    W1t[tid] = (bf16)W1[k * 512 + n];
  }
  if (tid < 128 * 512) {
    int n = tid >> 9;
    int k = tid & 511;
    W2t[tid] = (bf16)W2[k * 128 + n];
  }
}

__device__ __forceinline__ bf16x8 cvt8v(f32x4 a, f32x4 b) {
  bf16x8 r;
  r[0] = (bf16)a[0]; r[1] = (bf16)a[1]; r[2] = (bf16)a[2]; r[3] = (bf16)a[3];
  r[4] = (bf16)b[0]; r[5] = (bf16)b[1]; r[6] = (bf16)b[2]; r[7] = (bf16)b[3];
  return r;
}

// Fused: h = silu(concat(x_i,x_j,ea) @ W1 + b1); y = LN(h @ W2 + b2)*g + b + ea
//
// Barrier-free GEMM cores: A-fragments loaded per-wave directly from global
// (fp32, converted in-reg; 4-way inter-wave row redundancy absorbed by L1/L2),
// B-fragments loaded per-wave directly from the L2-resident bf16 weights.
// LDS is used ONLY for the H1 handoff (layout redistribution across SiLU),
// giving 2 barriers per nc chunk (8 total) instead of 64. 16 independent
// wave-streams per CU hide HBM latency by TLP.
__global__ __launch_bounds__(512, 4)
void fused_edge_mlp(const float* __restrict__ x_i,
                    const float* __restrict__ x_j,
                    const float* __restrict__ ea,
                    const bf16* __restrict__ W1t,
                    const float* __restrict__ b1,
                    const bf16* __restrict__ W2t,
                    const float* __restrict__ b2,
                    const float* __restrict__ gmm,
                    const float* __restrict__ bta,
                    float* __restrict__ out)
{
  __shared__ bf16 H1s[128 * 136];     // 34.8KB (+8 pad) -> LDS allows 2+ blocks/CU

  const int t    = threadIdx.x;
  const int w    = t >> 6;             // wave 0..7
  const int lane = t & 63;
  const int l15  = lane & 15;
  const int q    = lane >> 4;          // quad 0..3
  const int wm   = w >> 2;             // GEMM1 row half (64 rows)
  const int wn   = w & 3;              // GEMM1 col quarter (32 cols)
  const long m0  = (long)blockIdx.x * MT;

  const f32x4 fzero = {0.f, 0.f, 0.f, 0.f};

  f32x4 acc2[8];                       // C2 [16 x 128] per wave (rows 16w..16w+15)
  #pragma unroll
  for (int i = 0; i < 8; ++i) acc2[i] = fzero;

  // per-lane base offsets (elements)
  // A frag (mi): row m0 + 64*wm + 16*mi + l15, cols k4*32 + 8*q .. +8  (fp32, stride 128)
  const long aoff = (m0 + 64 * wm + l15) * 128 + 8 * q;
  // B frag (ni): W1t row nc*128 + 32*wn + 16*ni + l15, k-cols kk*32 + 8*q (bf16, stride 384)
  const long boff = (long)(32 * wn + l15) * 384 + 8 * q;

  for (int nc = 0; nc < 4; ++nc) {
    f32x4 acc1[8];                     // C1 [64 x 32] per wave
    #pragma unroll
    for (int i = 0; i < 8; ++i) acc1[i] = fzero;

    const bf16* Wb = W1t + (long)nc * 128 * 384 + boff;

    // ---- GEMM1: K=384 as 3 sources x 4 k-steps of 32; no LDS, no barriers ----
    for (int ph = 0; ph < 3; ++ph) {
      const float* src = (ph == 0) ? x_i : (ph == 1) ? x_j : ea;
      const float* Ab  = src + aoff;
      #pragma unroll
      for (int k4 = 0; k4 < 4; ++k4) {
        const int kk = ph * 4 + k4;
        // issue all global loads first (8 A-loads + 2 B-loads in flight)
        f32x4 a0[4], a1[4];
        #pragma unroll
        for (int mi = 0; mi < 4; ++mi) {
          const float* p = Ab + (long)mi * 16 * 128 + k4 * 32;
          a0[mi] = *(const f32x4*)p;
          a1[mi] = *(const f32x4*)(p + 4);
        }
        bf16x8 bfr[2];
        #pragma unroll
        for (int ni = 0; ni < 2; ++ni)
          bfr[ni] = *(const bf16x8*)(Wb + (long)ni * 16 * 384 + kk * 32);

        bf16x8 af[4];
        #pragma unroll
        for (int mi = 0; mi < 4; ++mi)
          af[mi] = cvt8v(a0[mi], a1[mi]);

        #pragma unroll
        for (int mi = 0; mi < 4; ++mi)
          #pragma unroll
          for (int ni = 0; ni < 2; ++ni)
            acc1[mi * 2 + ni] = __builtin_amdgcn_mfma_f32_16x16x32_bf16(
                af[mi], bfr[ni], acc1[mi * 2 + ni], 0, 0, 0);
      }
    }

    // ---- epilogue: bias + SiLU -> H1s (C/D layout -> row-major LDS) ----
    {
      float b1v[2];
      #pragma unroll
      for (int ni = 0; ni < 2; ++ni)
        b1v[ni] = b1[nc * 128 + 32 * wn + 16 * ni + l15];
      #pragma unroll
      for (int mi = 0; mi < 4; ++mi)
        #pragma unroll
        for (int ni = 0; ni < 2; ++ni)
          #pragma unroll
          for (int i = 0; i < 4; ++i) {
            float s = acc1[mi * 2 + ni][i] + b1v[ni];
            float h = s / (1.f + __expf(-s));
            H1s[(64 * wm + 16 * mi + 4 * q + i) * 136 + 32 * wn + 16 * ni + l15] = (bf16)h;
          }
    }
    __syncthreads();   // H1 chunk complete & visible

    // ---- GEMM2 partial: C2 += H1chunk[128,128] @ W2t(:, nc*128..)^T ----
    // a2 from LDS; W2 fragments straight from L2-resident W2t.
    const bf16* W2b = W2t + nc * 128 + (long)l15 * 512 + 8 * q;
    #pragma unroll
    for (int s4 = 0; s4 < 4; ++s4) {
      bf16x8 a2 = *(const bf16x8*)&H1s[(16 * w + l15) * 136 + (s4 << 5) + (q << 3)];
      #pragma unroll
      for (int ni = 0; ni < 8; ++ni) {
        bf16x8 b2f = *(const bf16x8*)(W2b + (long)ni * 16 * 512 + s4 * 32);
        acc2[ni] = __builtin_amdgcn_mfma_f32_16x16x32_bf16(a2, b2f, acc2[ni], 0, 0, 0);
      }
    }
    __syncthreads();   // GEMM2 reads done; next nc may overwrite H1s
  }

  // ---- LN + gamma/beta + residual; wave w owns rows [16w,16w+16) ----
  float b2v[8], gv[8], bv[8];
  #pragma unroll
  for (int ni = 0; ni < 8; ++ni) {
    int n = 16 * ni + l15;
    b2v[ni] = b2[n];
    gv[ni]  = gmm[n];
    bv[ni]  = bta[n];
  }
  #pragma unroll
  for (int ni = 0; ni < 8; ++ni)
    #pragma unroll
    for (int i = 0; i < 4; ++i)
      acc2[ni][i] += b2v[ni];

  #pragma unroll
  for (int i = 0; i < 4; ++i) {
    float s = 0.f, s2 = 0.f;
    #pragma unroll
    for (int ni = 0; ni < 8; ++ni) {
      float v = acc2[ni][i];
      s += v;
      s2 += v * v;
    }
    // reduce across the 16 lanes of this quad (row r=4q+i lives in one quad)
    #pragma unroll
    for (int off = 1; off <= 8; off <<= 1) {
      s  += __shfl_xor(s,  off, 64);
      s2 += __shfl_xor(s2, off, 64);
    }
    float mu   = s * (1.f / 128.f);
    float var  = fmaxf(s2 * (1.f / 128.f) - mu * mu, 0.f);
    float rstd = rsqrtf(var + 1e-5f);
    long  mg   = m0 + 16 * w + 4 * q + i;
    #pragma unroll
    for (int ni = 0; ni < 8; ++ni) {
      int n = 16 * ni + l15;
      float o = (acc2[ni][i] - mu) * rstd * gv[ni] + bv[ni] + ea[mg * 128 + n];
      out[mg * 128 + n] = o;
    }
  }
}

extern "C" void kernel_launch(void* const* d_in, const int* in_sizes, int n_in,
                              void* d_out, int out_size, void* d_ws, size_t ws_size,
                              hipStream_t stream)
{
  const float* x_i = (const float*)d_in[0];
  const float* x_j = (const float*)d_in[1];
  const float* ea  = (const float*)d_in[2];
  const float* W1  = (const float*)d_in[3];
  const float* b1  = (const float*)d_in[4];
  const float* W2  = (const float*)d_in[5];
  const float* b2  = (const float*)d_in[6];
  const float* gm  = (const float*)d_in[7];
  const float* bt  = (const float*)d_in[8];
  float* outp = (float*)d_out;
  bf16* W1t = (bf16*)d_ws;           // 512*384 bf16
  bf16* W2t = W1t + 512 * 384;       // 128*512 bf16

  hipLaunchKernelGGL(transpose_w, dim3(768), dim3(256), 0, stream, W1, W2, W1t, W2t);
  hipLaunchKernelGGL(fused_edge_mlp, dim3(E_EDGES / MT), dim3(512), 0, stream,
                     x_i, x_j, ea, W1t, b1, W2t, b2, gm, bt, outp);
}

// Round 4
// 864.982 us; speedup vs baseline: 1.6071x; 1.6071x over previous
//
#include <hip/hip_runtime.h>
#include <hip/hip_bf16.h>

typedef __bf16 bf16;
typedef __attribute__((ext_vector_type(8))) __bf16 bf16x8;
typedef __attribute__((ext_vector_type(4))) float f32x4;

#define E_EDGES 262144
#define MT 128   // rows per block

// Pre-pass: transpose + fp32->bf16 convert weights into workspace.
// W1 fp32 [384][512] -> W1t bf16 [512][384];  W2 fp32 [512][128] -> W2t bf16 [128][512]
__global__ void transpose_w(const float* __restrict__ W1, const float* __restrict__ W2,
                            bf16* __restrict__ W1t, bf16* __restrict__ W2t)
{
  int tid = blockIdx.x * 256 + threadIdx.x;
  if (tid < 512 * 384) {
    int n = tid / 384;
    int k = tid - n * 384;
    W1t[tid] = (bf16)W1[k * 512 + n];
  }
  if (tid < 128 * 512) {
    int n = tid >> 9;
    int k = tid & 511;
    W2t[tid] = (bf16)W2[k * 128 + n];
  }
}

__device__ __forceinline__ bf16x8 cvt8v(f32x4 a, f32x4 b) {
  bf16x8 r;
  r[0] = (bf16)a[0]; r[1] = (bf16)a[1]; r[2] = (bf16)a[2]; r[3] = (bf16)a[3];
  r[4] = (bf16)b[0]; r[5] = (bf16)b[1]; r[6] = (bf16)b[2]; r[7] = (bf16)b[3];
  return r;
}

// Fused: h = silu(concat(x_i,x_j,ea) @ W1 + b1); y = LN(h @ W2 + b2)*g + b + ea
//
// Structure (lessons R0-R3):
//  - A [128 x 384] staged ONCE per block into persistent swizzled LDS (96KB),
//    as one pipelined HBM burst + 1 barrier. No per-nc restaging.
//  - Weights (L2-resident: W1t 384KB, W2t 128KB) loaded per-wave directly
//    from global in MFMA fragment layout. No LDS staging, no barriers.
//  - GEMM1/GEMM2 inner loops are barrier-free; 9 barriers total per block
//    (vs 128 in R0), none draining HBM loads.
//  - 131KB LDS -> 1 block/CU, 2 waves/SIMD; launch_bounds(512,2) -> 256 VGPR
//    cap so the unrolled loops can hoist L2 loads without spilling.
__global__ __launch_bounds__(512, 2)
void fused_edge_mlp(const float* __restrict__ x_i,
                    const float* __restrict__ x_j,
                    const float* __restrict__ ea,
                    const bf16* __restrict__ W1t,
                    const float* __restrict__ b1,
                    const bf16* __restrict__ W2t,
                    const float* __restrict__ b2,
                    const float* __restrict__ gmm,
                    const float* __restrict__ bta,
                    float* __restrict__ out)
{
  __shared__ bf16 As[128 * 384];      // 96KB persistent A tile, XOR-swizzled
  __shared__ bf16 H1s[128 * 136];     // 34.8KB (+8 pad) H1 handoff

  const int t    = threadIdx.x;
  const int w    = t >> 6;             // wave 0..7
  const int lane = t & 63;
  const int l15  = lane & 15;
  const int q    = lane >> 4;          // quad 0..3
  const int srow = t >> 2;             // staging row 0..127 (4 threads/row)
  const int sc   = t & 3;              // staging 16B-block col 0..3
  const int wm   = w >> 2;             // GEMM1 row half (64 rows)
  const int wn   = w & 3;              // GEMM1 col quarter (32 cols)
  const long m0  = (long)blockIdx.x * MT;
  const int rsw  = l15 & 7;            // read-side swizzle term (row & 7)

  const f32x4 fzero = {0.f, 0.f, 0.f, 0.f};

  // ---- prologue: stage full A [128][384] as bf16, swizzled; one barrier ----
  // round r covers cols [32r, 32r+32) of concat(x_i,x_j,ea)
  #pragma unroll
  for (int r = 0; r < 12; ++r) {
    const float* src = (r < 4) ? x_i : (r < 8) ? x_j : ea;
    const float* p = src + (m0 + srow) * 128 + ((r & 3) << 5) + (sc << 3);
    f32x4 a0 = *(const f32x4*)p;
    f32x4 a1 = *(const f32x4*)(p + 4);
    const int c16 = (4 * r + sc) ^ (srow & 7);   // 16B-block col, swizzled
    *(bf16x8*)&As[srow * 384 + c16 * 8] = cvt8v(a0, a1);
  }
  __syncthreads();

  f32x4 acc2[8];                       // C2 [16 x 128] per wave (rows 16w..16w+15)
  #pragma unroll
  for (int i = 0; i < 8; ++i) acc2[i] = fzero;

  for (int nc = 0; nc < 4; ++nc) {
    f32x4 acc1[8];                     // C1 [64 x 32] per wave
    #pragma unroll
    for (int i = 0; i < 8; ++i) acc1[i] = fzero;

    // W1 fragment base: rows nc*128 + 32*wn + 16*ni + l15, 16B at col kk*32+8q
    const bf16* Wb = W1t + (long)(nc * 128 + 32 * wn + l15) * 384 + 8 * q;

    // ---- GEMM1: K=384, 12 k-steps; A from LDS, W1 from L2; barrier-free ----
    #pragma unroll
    for (int kk = 0; kk < 12; ++kk) {
      bf16x8 bfr[2];
      bfr[0] = *(const bf16x8*)(Wb + kk * 32);
      bfr[1] = *(const bf16x8*)(Wb + 16 * 384 + kk * 32);
      bf16x8 af[4];
      #pragma unroll
      for (int mi = 0; mi < 4; ++mi) {
        const int row = 64 * wm + 16 * mi + l15;
        const int c16 = (4 * kk + q) ^ rsw;
        af[mi] = *(const bf16x8*)&As[row * 384 + c16 * 8];
      }
      #pragma unroll
      for (int mi = 0; mi < 4; ++mi)
        #pragma unroll
        for (int ni = 0; ni < 2; ++ni)
          acc1[mi * 2 + ni] = __builtin_amdgcn_mfma_f32_16x16x32_bf16(
              af[mi], bfr[ni], acc1[mi * 2 + ni], 0, 0, 0);
    }

    // previous nc's GEMM2 readers must be done before overwriting H1s
    __syncthreads();

    // ---- epilogue: bias + SiLU -> H1s (C/D layout -> row-major LDS) ----
    {
      float b1v[2];
      #pragma unroll
      for (int ni = 0; ni < 2; ++ni)
        b1v[ni] = b1[nc * 128 + 32 * wn + 16 * ni + l15];
      #pragma unroll
      for (int mi = 0; mi < 4; ++mi)
        #pragma unroll
        for (int ni = 0; ni < 2; ++ni)
          #pragma unroll
          for (int i = 0; i < 4; ++i) {
            float s = acc1[mi * 2 + ni][i] + b1v[ni];
            float h = s / (1.f + __expf(-s));
            H1s[(64 * wm + 16 * mi + 4 * q + i) * 136 + 32 * wn + 16 * ni + l15] = (bf16)h;
          }
    }
    __syncthreads();   // H1 chunk visible

    // ---- GEMM2 partial: C2 += H1chunk[128,128] @ W2chunk^T; W2 from L2 ----
    const bf16* W2b = W2t + (long)l15 * 512 + nc * 128 + 8 * q;
    #pragma unroll
    for (int s4 = 0; s4 < 4; ++s4) {
      bf16x8 a2 = *(const bf16x8*)&H1s[(16 * w + l15) * 136 + (s4 << 5) + (q << 3)];
      #pragma unroll
      for (int ni = 0; ni < 8; ++ni) {
        bf16x8 b2f = *(const bf16x8*)(W2b + (long)ni * 16 * 512 + s4 * 32);
        acc2[ni] = __builtin_amdgcn_mfma_f32_16x16x32_bf16(a2, b2f, acc2[ni], 0, 0, 0);
      }
    }
    // no barrier here: next nc's GEMM1 touches only As; the barrier before
    // the next H1s overwrite is taken after that GEMM1 completes.
  }

  // ---- LN + gamma/beta + residual; wave w owns rows [16w,16w+16) ----
  float b2v[8], gv[8], bv[8];
  #pragma unroll
  for (int ni = 0; ni < 8; ++ni) {
    int n = 16 * ni + l15;
    b2v[ni] = b2[n];
    gv[ni]  = gmm[n];
    bv[ni]  = bta[n];
  }
  #pragma unroll
  for (int ni = 0; ni < 8; ++ni)
    #pragma unroll
    for (int i = 0; i < 4; ++i)
      acc2[ni][i] += b2v[ni];

  #pragma unroll
  for (int i = 0; i < 4; ++i) {
    float s = 0.f, s2 = 0.f;
    #pragma unroll
    for (int ni = 0; ni < 8; ++ni) {
      float v = acc2[ni][i];
      s += v;
      s2 += v * v;
    }
    // reduce across the 16 lanes of this quad (row r=4q+i lives in one quad)
    #pragma unroll
    for (int off = 1; off <= 8; off <<= 1) {
      s  += __shfl_xor(s,  off, 64);
      s2 += __shfl_xor(s2, off, 64);
    }
    float mu   = s * (1.f / 128.f);
    float var  = fmaxf(s2 * (1.f / 128.f) - mu * mu, 0.f);
    float rstd = rsqrtf(var + 1e-5f);
    long  mg   = m0 + 16 * w + 4 * q + i;
    #pragma unroll
    for (int ni = 0; ni < 8; ++ni) {
      int n = 16 * ni + l15;
      float o = (acc2[ni][i] - mu) * rstd * gv[ni] + bv[ni] + ea[mg * 128 + n];
      out[mg * 128 + n] = o;
    }
  }
}

extern "C" void kernel_launch(void* const* d_in, const int* in_sizes, int n_in,
                              void* d_out, int out_size, void* d_ws, size_t ws_size,
                              hipStream_t stream)
{
  const float* x_i = (const float*)d_in[0];
  const float* x_j = (const float*)d_in[1];
  const float* ea  = (const float*)d_in[2];
  const float* W1  = (const float*)d_in[3];
  const float* b1  = (const float*)d_in[4];
  const float* W2  = (const float*)d_in[5];
  const float* b2  = (const float*)d_in[6];
  const float* gm  = (const float*)d_in[7];
  const float* bt  = (const float*)d_in[8];
  float* outp = (float*)d_out;
  bf16* W1t = (bf16*)d_ws;           // 512*384 bf16
  bf16* W2t = W1t + 512 * 384;       // 128*512 bf16

  hipLaunchKernelGGL(transpose_w, dim3(768), dim3(256), 0, stream, W1, W2, W1t, W2t);
  hipLaunchKernelGGL(fused_edge_mlp, dim3(E_EDGES / MT), dim3(512), 0, stream,
                     x_i, x_j, ea, W1t, b1, W2t, b2, gm, bt, outp);
}

// Round 5
// 688.211 us; speedup vs baseline: 2.0199x; 1.2569x over previous
//
#include <hip/hip_runtime.h>
#include <hip/hip_bf16.h>

typedef __bf16 bf16;
typedef __attribute__((ext_vector_type(8))) __bf16 bf16x8;
typedef __attribute__((ext_vector_type(4))) float f32x4;

#define E_EDGES 262144
#define MT 128   // rows per block

#define VMW(n)  asm volatile("s_waitcnt vmcnt(" #n ")" ::: "memory")
#define LGKM0   asm volatile("s_waitcnt lgkmcnt(0)" ::: "memory")
#define MEMF    asm volatile("" ::: "memory")
#define BAR     __builtin_amdgcn_s_barrier()
#define SCHEDB  __builtin_amdgcn_sched_barrier(0)

// Pre-pass: transpose + fp32->bf16 convert weights into workspace.
// W1 fp32 [384][512] -> W1t bf16 [512][384];  W2 fp32 [512][128] -> W2t bf16 [128][512]
__global__ void transpose_w(const float* __restrict__ W1, const float* __restrict__ W2,
                            bf16* __restrict__ W1t, bf16* __restrict__ W2t)
{
  int tid = blockIdx.x * 256 + threadIdx.x;
  if (tid < 512 * 384) {
    int n = tid / 384;
    int k = tid - n * 384;
    W1t[tid] = (bf16)W1[k * 512 + n];
  }
  if (tid < 128 * 512) {
    int n = tid >> 9;
    int k = tid & 511;
    W2t[tid] = (bf16)W2[k * 128 + n];
  }
}

__device__ __forceinline__ bf16x8 cvt8v(f32x4 a, f32x4 b) {
  bf16x8 r;
  r[0] = (bf16)a[0]; r[1] = (bf16)a[1]; r[2] = (bf16)a[2]; r[3] = (bf16)a[3];
  r[4] = (bf16)b[0]; r[5] = (bf16)b[1]; r[6] = (bf16)b[2]; r[7] = (bf16)b[3];
  return r;
}

// async global->LDS, 16B per lane; LDS dest is wave-uniform base + lane*16
__device__ __forceinline__ void glds16(const void* g, void* l) {
  __builtin_amdgcn_global_load_lds(
      (const __attribute__((address_space(1))) void*)g,
      (__attribute__((address_space(3))) void*)l,
      16, 0, 0);
}

// Fused: h = silu(concat(x_i,x_j,ea) @ W1 + b1); y = LN(h @ W2 + b2)*g + b + ea
//
// Schedule: per nc chunk, 16 steps (12 GEMM1-K + 4 GEMM2). ALL staging via
// global_load_lds (zero staging VGPRs; A staged as fp32, converted at the
// LDS->fragment read). 3-slot rotation per operand stream (A, W1, W2) gives
// every load 2 full steps of latency cover. One raw s_barrier per step with
// counted vmcnt (never drained to 0 in the loop). Fully static periodic
// slot/ledger pattern. 130.8KB LDS -> 1 block/CU; latency hidden by the
// pipeline, not TLP.
__global__ __launch_bounds__(512, 2)
void fused_edge_mlp(const float* __restrict__ x_i,
                    const float* __restrict__ x_j,
                    const float* __restrict__ ea,
                    const bf16* __restrict__ W1t,
                    const float* __restrict__ b1,
                    const bf16* __restrict__ W2t,
                    const float* __restrict__ b2,
                    const float* __restrict__ gmm,
                    const float* __restrict__ bta,
                    float* __restrict__ out)
{
  __shared__ float Asf[3][128 * 32];   // 48KB: A k-tiles, fp32, XOR-swizzled
  __shared__ bf16  Bsb[3][128 * 32];   // 24KB: W1 k-tiles, bf16, XOR-swizzled
  __shared__ bf16  Wsb[3][128 * 32];   // 24KB: W2 k-tiles, bf16, XOR-swizzled
  __shared__ bf16  H1s[128 * 136];     // 34.8KB (+8 pad) H1 handoff

  const int t    = threadIdx.x;
  const int w    = t >> 6;             // wave 0..7
  const int lane = t & 63;
  const int l15  = lane & 15;
  const int q    = lane >> 4;          // quad 0..3
  const int wm   = w >> 2;             // GEMM1 row half (64 rows)
  const int wn   = w & 3;              // GEMM1 col quarter (32 cols)
  const long m0  = (long)blockIdx.x * MT;

  // staging geometry (glds16 writes LDS linearly: byte = t*16 within an issue)
  const int sr8  = t >> 3;                         // A: row (issue0) / row-64 (issue1)
  const int ab   = ((t & 7) ^ (sr8 & 7)) << 2;     // A: swizzled fp32 col offset
  const int sr4  = t >> 2;                         // B/W2: row 0..127
  const int bb   = (((t & 3) ^ ((sr4 >> 1) & 3)) << 3); // B: swizzled bf16 col offset
  const int wlds = w * 1024;                       // wave-uniform byte base per issue

  const f32x4 fzero = {0.f, 0.f, 0.f, 0.f};

  // preload b1 for all 4 nc chunks (static indices only; selected by cndmask later)
  float b1r[8];
  #pragma unroll
  for (int j = 0; j < 8; ++j)
    b1r[j] = b1[(j >> 1) * 128 + 32 * wn + 16 * (j & 1) + l15];

  f32x4 acc2[8];                       // C2 [16 x 128] per wave (rows 16w..16w+15)
  #pragma unroll
  for (int i = 0; i < 8; ++i) acc2[i] = fzero;

  // A-tile stage: 2 glds16 (16KB fp32 tile), swizzled source, linear dest
  #define STAGE_A(sl, srcp, kb) do {                                        \
    glds16((srcp) + (m0 + sr8) * 128 + (kb) + ab,                           \
           (char*)&Asf[sl][0] + wlds);                                      \
    glds16((srcp) + (m0 + 64 + sr8) * 128 + (kb) + ab,                      \
           (char*)&Asf[sl][0] + 8192 + wlds);                               \
  } while (0)

  // ---- prologue: stage steps 0 and 1 of nc=0 ----
  glds16(W1t + (long)sr4 * 384 + 0  + bb, (char*)&Bsb[0][0] + wlds);
  STAGE_A(0, x_i, 0);
  glds16(W1t + (long)sr4 * 384 + 32 + bb, (char*)&Bsb[1][0] + wlds);
  STAGE_A(1, x_i, 32);
  VMW(3);                 // step-0 tiles resident; step-1 still in flight
  BAR; MEMF;

  for (int nc = 0; nc < 4; ++nc) {
    f32x4 acc1[8];                     // C1 [64 x 32] per wave
    #pragma unroll
    for (int i = 0; i < 8; ++i) acc1[i] = fzero;

    // ================= GEMM1: 12 K-steps =================
    #pragma unroll
    for (int j = 0; j < 12; ++j) {
      const int sl = j % 3;

      // ---- stage for step j+2 ----
      if (j < 10) {
        const int tt = j + 2;
        const float* srcp = (tt < 4) ? x_i : (tt < 8) ? x_j : ea;
        const int kb = (tt & 3) << 5;
        glds16(W1t + (long)(nc * 128 + sr4) * 384 + (tt << 5) + bb,
               (char*)&Bsb[tt % 3][0] + wlds);
        STAGE_A(tt % 3, srcp, kb);
      } else {
        const int c = j - 10;          // W2 chunk 0 (j=10), 1 (j=11)
        glds16(W2t + (long)sr4 * 512 + (nc << 7) + (c << 5) + bb,
               (char*)&Wsb[c % 3][0] + wlds);
      }

      // ---- compute G1 step j: A from Asf[sl] (fp32->bf16), B from Bsb[sl] ----
      bf16x8 bfr[2], af[4];
      #pragma unroll
      for (int ni = 0; ni < 2; ++ni) {
        const int r = 32 * wn + 16 * ni + l15;
        bfr[ni] = *(const bf16x8*)&Bsb[sl][r * 32 + ((q ^ ((r >> 1) & 3)) << 3)];
      }
      #pragma unroll
      for (int mi = 0; mi < 4; ++mi) {
        const int r = 64 * wm + 16 * mi + l15;
        const int m = r & 7;
        const float* ap = &Asf[sl][r * 32];
        f32x4 v0 = *(const f32x4*)(ap + (((2 * q)     ^ m) << 2));
        f32x4 v1 = *(const f32x4*)(ap + (((2 * q + 1) ^ m) << 2));
        af[mi] = cvt8v(v0, v1);
      }
      __builtin_amdgcn_s_setprio(1);
      #pragma unroll
      for (int mi = 0; mi < 4; ++mi)
        #pragma unroll
        for (int ni = 0; ni < 2; ++ni)
          acc1[mi * 2 + ni] = __builtin_amdgcn_mfma_f32_16x16x32_bf16(
              af[mi], bfr[ni], acc1[mi * 2 + ni], 0, 0, 0);
      __builtin_amdgcn_s_setprio(0);

      // ---- epilogue at j==11: bias + SiLU -> H1s ----
      if (j == 11) {
        float b1v0 = (nc == 0) ? b1r[0] : (nc == 1) ? b1r[2] : (nc == 2) ? b1r[4] : b1r[6];
        float b1v1 = (nc == 0) ? b1r[1] : (nc == 1) ? b1r[3] : (nc == 2) ? b1r[5] : b1r[7];
        #pragma unroll
        for (int mi = 0; mi < 4; ++mi)
          #pragma unroll
          for (int ni = 0; ni < 2; ++ni)
            #pragma unroll
            for (int i = 0; i < 4; ++i) {
              float s = acc1[mi * 2 + ni][i] + (ni ? b1v1 : b1v0);
              float h = s / (1.f + __expf(-s));
              H1s[(64 * wm + 16 * mi + 4 * q + i) * 136 + 32 * wn + 16 * ni + l15] = (bf16)h;
            }
      }

      LGKM0;                       // own ds-reads/writes drained before barrier
      if (j < 10) { VMW(3); } else { VMW(1); }   // stage(j+1) fully resident
      SCHEDB;
      BAR; MEMF;
    }

    // ================= GEMM2: 4 steps =================
    #pragma unroll
    for (int s4 = 0; s4 < 4; ++s4) {
      // ---- stage ----
      if (s4 < 2) {
        const int c = s4 + 2;          // W2 chunk 2 (s4=0), 3 (s4=1)
        glds16(W2t + (long)sr4 * 512 + (nc << 7) + (c << 5) + bb,
               (char*)&Wsb[c % 3][0] + wlds);
      } else if (nc < 3) {
        const int tt = s4 - 2;         // next nc steps 0,1
        glds16(W1t + (long)((nc + 1) * 128 + sr4) * 384 + (tt << 5) + bb,
               (char*)&Bsb[tt][0] + wlds);
        STAGE_A(tt, x_i, tt << 5);
      }

      // ---- compute G2 step s4: a2 from H1s, W2 frags from Wsb[s4%3] ----
      const int sl = s4 % 3;
      bf16x8 a2 = *(const bf16x8*)&H1s[(16 * w + l15) * 136 + (s4 << 5) + (q << 3)];
      __builtin_amdgcn_s_setprio(1);
      #pragma unroll
      for (int ni = 0; ni < 8; ++ni) {
        const int r = 16 * ni + l15;
        bf16x8 b2f = *(const bf16x8*)&Wsb[sl][r * 32 + ((q ^ ((r >> 1) & 3)) << 3)];
        acc2[ni] = __builtin_amdgcn_mfma_f32_16x16x32_bf16(a2, b2f, acc2[ni], 0, 0, 0);
      }
      __builtin_amdgcn_s_setprio(0);

      LGKM0;
      if (s4 < 2)      { VMW(1); }
      else if (nc < 3) { VMW(3); }
      else             { VMW(0); }     // tail of last nc only
      SCHEDB;
      BAR; MEMF;
    }
  }

  // ---- LN + gamma/beta + residual; wave w owns rows [16w,16w+16) ----
  float b2v[8], gv[8], bv[8];
  #pragma unroll
  for (int ni = 0; ni < 8; ++ni) {
    int n = 16 * ni + l15;
    b2v[ni] = b2[n];
    gv[ni]  = gmm[n];
    bv[ni]  = bta[n];
  }
  #pragma unroll
  for (int ni = 0; ni < 8; ++ni)
    #pragma unroll
    for (int i = 0; i < 4; ++i)
      acc2[ni][i] += b2v[ni];

  #pragma unroll
  for (int i = 0; i < 4; ++i) {
    float s = 0.f, s2 = 0.f;
    #pragma unroll
    for (int ni = 0; ni < 8; ++ni) {
      float v = acc2[ni][i];
      s += v;
      s2 += v * v;
    }
    // reduce across the 16 lanes of this quad (row r=4q+i lives in one quad)
    #pragma unroll
    for (int off = 1; off <= 8; off <<= 1) {
      s  += __shfl_xor(s,  off, 64);
      s2 += __shfl_xor(s2, off, 64);
    }
    float mu   = s * (1.f / 128.f);
    float var  = fmaxf(s2 * (1.f / 128.f) - mu * mu, 0.f);
    float rstd = rsqrtf(var + 1e-5f);
    long  mg   = m0 + 16 * w + 4 * q + i;
    #pragma unroll
    for (int ni = 0; ni < 8; ++ni) {
      int n = 16 * ni + l15;
      float o = (acc2[ni][i] - mu) * rstd * gv[ni] + bv[ni] + ea[mg * 128 + n];
      out[mg * 128 + n] = o;
    }
  }
}

extern "C" void kernel_launch(void* const* d_in, const int* in_sizes, int n_in,
                              void* d_out, int out_size, void* d_ws, size_t ws_size,
                              hipStream_t stream)
{
  const float* x_i = (const float*)d_in[0];
  const float* x_j = (const float*)d_in[1];
  const float* ea  = (const float*)d_in[2];
  const float* W1  = (const float*)d_in[3];
  const float* b1  = (const float*)d_in[4];
  const float* W2  = (const float*)d_in[5];
  const float* b2  = (const float*)d_in[6];
  const float* gm  = (const float*)d_in[7];
  const float* bt  = (const float*)d_in[8];
  float* outp = (float*)d_out;
  bf16* W1t = (bf16*)d_ws;           // 512*384 bf16
  bf16* W2t = W1t + 512 * 384;       // 128*512 bf16

  hipLaunchKernelGGL(transpose_w, dim3(768), dim3(256), 0, stream, W1, W2, W1t, W2t);
  hipLaunchKernelGGL(fused_edge_mlp, dim3(E_EDGES / MT), dim3(512), 0, stream,
                     x_i, x_j, ea, W1t, b1, W2t, b2, gm, bt, outp);
}